// Round 7
// baseline (434.218 us; speedup 1.0000x reference)
//
#include <hip/hip_runtime.h>
#include <hip/hip_bf16.h>

// SFM model: B=256, T=128, D=128, FREQ=16, HID=128
// Phase 1: P[(b*128+t)*528 + c] = x(b,t,:) @ [W_i|W_ste|W_c|W_o|W_fre] + bias
//   256 thr/block, 8x8 register tile per thread (1.0 LDS-byte/MAC, X reads broadcast).
// Phase 2: sequential scan. 1024 thr/block, 1 batch/block. Each thread holds a
//   64-element half-column of one U matrix in VGPRs. volatile init loads forbid
//   rematerialization; __launch_bounds__(1024,4) gives the 128-VGPR budget.

__device__ __forceinline__ float hsig_f(float z) {
    return fminf(fmaxf(z * (1.0f / 6.0f) + 0.5f, 0.0f), 1.0f);
}

// ---------------- Phase 1: projection GEMM ----------------
// grid = 256 (one batch each), block = 256. LDS: X tile 64KB + W tile 64KB.
__global__ __launch_bounds__(256, 2) void proj_gemm(
    const float* __restrict__ input,
    const float* __restrict__ Wi, const float* __restrict__ Wste,
    const float* __restrict__ Wc, const float* __restrict__ Wo,
    const float* __restrict__ Wfre,
    const float* __restrict__ bi, const float* __restrict__ bste,
    const float* __restrict__ bc, const float* __restrict__ bo,
    const float* __restrict__ bfre,
    float* __restrict__ P)
{
    __shared__ __align__(16) float XT[128 * 128];  // [d][t]
    __shared__ __align__(16) float WT[128 * 128];  // [d][c]

    const int b   = blockIdx.x;
    const int tid = threadIdx.x;

    // Stage X once: input[b*16384 + d*128 + t] is already [d][t] contiguous.
    const float* xb = input + (size_t)b * 16384;
#pragma unroll
    for (int i = 0; i < 16; i++) {
        int idx4 = (i * 256 + tid) * 4;
        *(float4*)(&XT[idx4]) = *(const float4*)(xb + idx4);
    }

    const int tx = tid & 15, ty = tid >> 4;
    const int c0 = tx * 8, t0 = ty * 8;

    const float* Ws[5]     = {Wi, Wste, Wc, Wo, Wfre};
    const float* biases[5] = {bi, bste, bc, bo, bfre};

    for (int ct = 0; ct < 5; ct++) {
        const float* W = Ws[ct];
        if (ct < 4) {
#pragma unroll
            for (int i = 0; i < 16; i++) {
                int idx4 = (i * 256 + tid) * 4;
                *(float4*)(&WT[idx4]) = *(const float4*)(W + idx4);
            }
        } else {
            // Wfre: 128x16 -> WT[d*128 + cc] (cc<16)
#pragma unroll
            for (int i = 0; i < 2; i++) {
                int idx4 = (i * 256 + tid) * 4;
                int d = idx4 >> 4, cc = idx4 & 15;
                *(float4*)(&WT[d * 128 + cc]) = *(const float4*)(W + idx4);
            }
        }
        __syncthreads();

        float acc[8][8] = {};
#pragma unroll 2
        for (int k = 0; k < 128; k++) {
            float4 x0 = *(const float4*)(&XT[k * 128 + t0]);
            float4 x1 = *(const float4*)(&XT[k * 128 + t0 + 4]);
            float4 w0 = *(const float4*)(&WT[k * 128 + c0]);
            float4 w1 = *(const float4*)(&WT[k * 128 + c0 + 4]);
            const float xr[8] = {x0.x, x0.y, x0.z, x0.w, x1.x, x1.y, x1.z, x1.w};
            const float wc[8] = {w0.x, w0.y, w0.z, w0.w, w1.x, w1.y, w1.z, w1.w};
#pragma unroll
            for (int r = 0; r < 8; r++)
#pragma unroll
                for (int cc = 0; cc < 8; cc++)
                    acc[r][cc] = fmaf(xr[r], wc[cc], acc[r][cc]);
        }

        const int  cbase = (ct < 4) ? ct * 128 : 512;
        const bool valid = (ct < 4) || (c0 < 16);
        if (valid) {
            const float* bias = biases[ct];
            float4 b40, b41;
            b40.x = bias[c0 + 0]; b40.y = bias[c0 + 1];
            b40.z = bias[c0 + 2]; b40.w = bias[c0 + 3];
            b41.x = bias[c0 + 4]; b41.y = bias[c0 + 5];
            b41.z = bias[c0 + 6]; b41.w = bias[c0 + 7];
#pragma unroll
            for (int r = 0; r < 8; r++) {
                int row = b * 128 + t0 + r;
                float4 o0, o1;
                o0.x = acc[r][0] + b40.x; o0.y = acc[r][1] + b40.y;
                o0.z = acc[r][2] + b40.z; o0.w = acc[r][3] + b40.w;
                o1.x = acc[r][4] + b41.x; o1.y = acc[r][5] + b41.y;
                o1.z = acc[r][6] + b41.z; o1.w = acc[r][7] + b41.w;
                *(float4*)(&P[(size_t)row * 528 + cbase + c0])     = o0;
                *(float4*)(&P[(size_t)row * 528 + cbase + c0 + 4]) = o1;
            }
        }
        __syncthreads();  // WT reused next ct
    }
}

// ---------------- Phase 2: sequential recurrence ----------------
// 1024 threads. tid -> half = tid>>9 (k-split), c = tid&511, m = c>>7, j = c&127.
// State ownership: hh = tid>>3 (0..127), fsel = tid&7 -> freqs {fsel, fsel+8}.
__global__ __launch_bounds__(1024, 4) void recur_kernel(
    const float* __restrict__ P,
    const float* __restrict__ Ui, const float* __restrict__ Uste,
    const float* __restrict__ Uc, const float* __restrict__ Uo,
    const float* __restrict__ Ufre,
    const float* __restrict__ Ua, const float* __restrict__ ba_g,
    const float* __restrict__ Wsym, const float* __restrict__ bsym,
    float* __restrict__ out)
{
    __shared__ float ufre_t[16 * 132];   // [col][k]
    __shared__ float costab[16], sintab[16];
    __shared__ float gate_buf[512];      // [i|ste|c|o] x 128
    __shared__ float partial_buf[512];   // half-1 matvec partials
    __shared__ float fre_buf[16];
    __shared__ float h_buf[128];

    const int tid  = threadIdx.x;
    const int lane = tid & 63;
    const int half = tid >> 9;
    const int c    = tid & 511;
    const int m    = c >> 7;
    const int j    = c & 127;
    const int hh   = tid >> 3;     // 0..127
    const int fsel = tid & 7;      // freqs fsel, fsel+8
    const int b    = blockIdx.x;

    // one-time LDS init
    for (int e = tid; e < 2048; e += 1024) {
        int k = e >> 4, col = e & 15;
        ufre_t[col * 132 + k] = Ufre[e];
    }
    if (tid < 16) {
        float ang = 6.283185307179586f * (float)tid * (1.0f / 16.0f);
        costab[tid] = cosf(ang);
        sintab[tid] = sinf(ang);
    }
    if (tid < 128) h_buf[tid] = 0.0f;

    // 64-element half-column of U in registers (coalesced over j).
    // volatile: loads cannot be rematerialized/sunk into the t-loop -> the 64
    // values MUST be register-resident (budget 128 VGPR via launch_bounds).
    const float* Uptr = (m == 0) ? Ui : (m == 1) ? Uste : (m == 2) ? Uc : Uo;
    const volatile float* Uv = (const volatile float*)Uptr;
    float Ucol[64];
#pragma unroll
    for (int k = 0; k < 64; k++) Ucol[k] = Uv[(half * 64 + k) * 128 + j];

    const float ua0 = Ua[fsel];
    const float ua1 = Ua[fsel + 8];
    const float ba  = ba_g[hh];

    float hA = 0.0f;               // h[half*64 + lane], wave-replicated
    float Sre0 = 0.f, Sim0 = 0.f, Sre1 = 0.f, Sim1 = 0.f;
    int idx0 = 0, idx1 = 0;

    __syncthreads();

    const float* pr = P + (size_t)b * 128 * 528;
    for (int t = 0; t < 128; t++) {
        // global prefetch (consumed after barrier 1 — latency hidden by matvec)
        const float xpre = (half == 0) ? pr[c] : pr[512 + (c >> 5)];

        // ---- matvec partial: acc = sum_{k in half} h[k] * U[k][j] ----
        float a0 = 0.f, a1 = 0.f;
#pragma unroll
        for (int kk = 0; kk < 64; kk += 2) {
            float s0 = __uint_as_float(__builtin_amdgcn_readlane(__float_as_uint(hA), kk));
            float s1 = __uint_as_float(__builtin_amdgcn_readlane(__float_as_uint(hA), kk + 1));
            a0 = fmaf(s0, Ucol[kk],     a0);
            a1 = fmaf(s1, Ucol[kk + 1], a1);
        }
        float acc = a0 + a1;

        if (half) partial_buf[c] = acc;
        __syncthreads();  // B1: partials visible

        if (half == 0) {
            float z = acc + partial_buf[c] + xpre;
            float g = (m == 2) ? tanhf(z) : hsig_f(z);
            gate_buf[c] = g;
        } else {
            // fre gate: col = c>>5, 32 threads per col, 4 k's each (h_buf still old h)
            const int col = c >> 5, kg = c & 31;
            float4 hv = *(const float4*)(&h_buf[kg * 4]);
            float4 uv = *(const float4*)(&ufre_t[col * 132 + kg * 4]);
            float p = fmaf(hv.x, uv.x, fmaf(hv.y, uv.y, fmaf(hv.z, uv.z, hv.w * uv.w)));
#pragma unroll
            for (int off = 1; off <= 16; off <<= 1) p += __shfl_xor(p, off, 64);
            if (kg == 0) fre_buf[col] = hsig_f(p + xpre);
        }
        __syncthreads();  // B2: gates + fre ready

        // ---- state update: thread owns (hh, freqs fsel & fsel+8) ----
        {
            float iv = gate_buf[hh];
            float sv = gate_buf[128 + hh];
            float tc = gate_buf[256 + hh];
            float ov = gate_buf[384 + hh];
            float cg = iv * tc;

            idx0 = (idx0 + fsel) & 15;
            idx1 = (idx1 + fsel + 8) & 15;

            float f0v = sv * fre_buf[fsel];
            float f1v = sv * fre_buf[fsel + 8];
            Sre0 = fmaf(f0v, Sre0, cg * costab[idx0]);
            Sim0 = fmaf(f0v, Sim0, cg * sintab[idx0]);
            Sre1 = fmaf(f1v, Sre1, cg * costab[idx1]);
            Sim1 = fmaf(f1v, Sim1, cg * sintab[idx1]);

            float aacc = fmaf(Sre0, Sre0, Sim0 * Sim0) * ua0;
            aacc = fmaf(fmaf(Sre1, Sre1, Sim1 * Sim1), ua1, aacc);
            aacc += __shfl_xor(aacc, 1, 64);
            aacc += __shfl_xor(aacc, 2, 64);
            aacc += __shfl_xor(aacc, 4, 64);
            if (fsel == 0) {
                float a = tanhf(aacc + ba);
                h_buf[hh] = ov * a;
            }
        }
        __syncthreads();  // B3: h ready
        hA = h_buf[half * 64 + lane];
        pr += 528;
    }

    // ---- output: out[b] = h @ W_sym + b_sym ----
    if (tid < 64) {
        float v = fmaf(h_buf[lane], Wsym[lane], h_buf[64 + lane] * Wsym[64 + lane]);
#pragma unroll
        for (int off = 1; off <= 32; off <<= 1) v += __shfl_xor(v, off, 64);
        if (lane == 0) out[b] = v + bsym[0];
    }
}

extern "C" void kernel_launch(void* const* d_in, const int* in_sizes, int n_in,
                              void* d_out, int out_size, void* d_ws, size_t ws_size,
                              hipStream_t stream) {
    const float* input = (const float*)d_in[0];
    const float* W_i   = (const float*)d_in[1];
    const float* U_i   = (const float*)d_in[2];
    const float* b_i   = (const float*)d_in[3];
    const float* W_ste = (const float*)d_in[4];
    const float* U_ste = (const float*)d_in[5];
    const float* b_ste = (const float*)d_in[6];
    const float* W_fre = (const float*)d_in[7];
    const float* U_fre = (const float*)d_in[8];
    const float* b_fre = (const float*)d_in[9];
    const float* W_c   = (const float*)d_in[10];
    const float* U_c   = (const float*)d_in[11];
    const float* b_c   = (const float*)d_in[12];
    const float* W_o   = (const float*)d_in[13];
    const float* U_o   = (const float*)d_in[14];
    const float* b_o   = (const float*)d_in[15];
    const float* U_a   = (const float*)d_in[16];
    const float* b_a   = (const float*)d_in[17];
    const float* W_sym = (const float*)d_in[18];
    const float* b_sym = (const float*)d_in[19];

    float* P = (float*)d_ws;  // 32768 x 528 fp32 = 69.2 MB

    proj_gemm<<<256, 256, 0, stream>>>(
        input, W_i, W_ste, W_c, W_o, W_fre,
        b_i, b_ste, b_c, b_o, b_fre, P);

    recur_kernel<<<256, 1024, 0, stream>>>(
        P, U_i, U_ste, U_c, U_o, U_fre,
        U_a, b_a, W_sym, b_sym, (float*)d_out);
}

// Round 9
// 412.387 us; speedup vs baseline: 1.0529x; 1.0529x over previous
//
#include <hip/hip_runtime.h>
#include <hip/hip_bf16.h>

// SFM model: B=256, T=128, D=128, FREQ=16, HID=128
// Phase 1: P[(b*128+t)*528 + c] = x(b,t,:) @ [W_i|W_ste|W_c|W_o|W_fre] + bias
//   grid 512 (64 rows/block -> 2 blocks/CU), 256 thr, 8x2 tile/thread.
//   X LDS reads are wave-broadcast; W LDS reads 2-way (free) via 2-dword stride.
// Phase 2: sequential scan, 1024 thr/block, 1 batch/block.
//   amdgpu_waves_per_eu(4,4) pins 1 block/CU -> 128-VGPR budget so the
//   64-element U half-column actually lives in registers (round 4/7: VGPR=56,
//   U streamed from L2 = 8.6 GB = the whole 264 us).

__device__ __forceinline__ float hsig_f(float z) {
    return fminf(fmaxf(z * (1.0f / 6.0f) + 0.5f, 0.0f), 1.0f);
}

// ---------------- Phase 1: projection GEMM ----------------
__global__ __launch_bounds__(256) void proj_gemm(
    const float* __restrict__ input,
    const float* __restrict__ Wi, const float* __restrict__ Wste,
    const float* __restrict__ Wc, const float* __restrict__ Wo,
    const float* __restrict__ Wfre,
    const float* __restrict__ bi, const float* __restrict__ bste,
    const float* __restrict__ bc, const float* __restrict__ bo,
    const float* __restrict__ bfre,
    float* __restrict__ P)
{
    __shared__ __align__(16) float XT[128 * 64];  // [k][t]  32 KB
    __shared__ __align__(16) float WT[128 * 66];  // [k][c]  stride 66 dwords, 33.8 KB

    const int br  = blockIdx.x;          // 512 blocks: 64 rows each
    const int b   = br >> 1;
    const int t0g = (br & 1) * 64;
    const int tid = threadIdx.x;

    // Stage X tile: XT[k][t] = input[b*16384 + k*128 + t0g + t]
    const float* xb = input + (size_t)b * 16384 + t0g;
#pragma unroll
    for (int i = 0; i < 8; i++) {
        int f = (i * 256 + tid) * 4;
        int k = f >> 6, t = f & 63;
        *(float4*)(&XT[k * 64 + t]) = *(const float4*)(xb + k * 128 + t);
    }

    const int tx = tid & 31;   // col pair: c = tx*2, tx*2+1
    const int ty = tid >> 5;   // row group: rows ty*8 .. ty*8+7

    const float* Ws[5]     = {Wi, Wste, Wc, Wo, Wfre};
    const float* biases[5] = {bi, bste, bc, bo, bfre};

    for (int ct = 0; ct < 5; ct++) {
        const float* W     = Ws[ct];
        const float* bias  = biases[ct];
        const int    ncols = (ct < 4) ? 128 : 16;
        const int    npass = (ct < 4) ? 2 : 1;
        const int    cbase = (ct < 4) ? ct * 128 : 512;

        for (int ch = 0; ch < npass; ch++) {
            __syncthreads();   // protect WT from previous pass's readers
            // Stage W half-tile: WT[k][c] = W[k*ncols + ch*64 + c], c<64
#pragma unroll
            for (int i = 0; i < 8; i++) {
                int f = (i * 256 + tid) * 4;
                int k = f >> 6, c = f & 63;
                int gc = ch * 64 + c;
                if (gc < ncols)
                    *(float4*)(&WT[k * 66 + c]) = *(const float4*)(W + k * ncols + gc);
            }
            __syncthreads();

            float acc[8][2] = {};
#pragma unroll 4
            for (int k = 0; k < 128; k++) {
                float2 w  = *(const float2*)(&WT[k * 66 + tx * 2]);
                float4 x0 = *(const float4*)(&XT[k * 64 + ty * 8]);
                float4 x1 = *(const float4*)(&XT[k * 64 + ty * 8 + 4]);
                const float xr[8] = {x0.x, x0.y, x0.z, x0.w, x1.x, x1.y, x1.z, x1.w};
#pragma unroll
                for (int r = 0; r < 8; r++) {
                    acc[r][0] = fmaf(xr[r], w.x, acc[r][0]);
                    acc[r][1] = fmaf(xr[r], w.y, acc[r][1]);
                }
            }

            const int colg = ch * 64 + tx * 2;
            if (colg < ncols) {
                float b0 = bias[colg], b1 = bias[colg + 1];
#pragma unroll
                for (int r = 0; r < 8; r++) {
                    int row = br * 64 + ty * 8 + r;
                    float2 o = make_float2(acc[r][0] + b0, acc[r][1] + b1);
                    *(float2*)(&P[(size_t)row * 528 + cbase + colg]) = o;
                }
            }
        }
    }
}

// ---------------- Phase 2: sequential recurrence ----------------
// 1024 threads. tid -> half = tid>>9 (k-split), c = tid&511, m = c>>7, j = c&127.
// State ownership: hh = tid>>3 (0..127), fsel = tid&7 -> freqs {fsel, fsel+8}.
__global__
__attribute__((amdgpu_flat_work_group_size(1024, 1024)))
__attribute__((amdgpu_waves_per_eu(4, 4)))
void recur_kernel(
    const float* __restrict__ P,
    const float* __restrict__ Ui, const float* __restrict__ Uste,
    const float* __restrict__ Uc, const float* __restrict__ Uo,
    const float* __restrict__ Ufre,
    const float* __restrict__ Ua, const float* __restrict__ ba_g,
    const float* __restrict__ Wsym, const float* __restrict__ bsym,
    float* __restrict__ out)
{
    __shared__ float ufre_t[16 * 132];   // [col][k]
    __shared__ float costab[16], sintab[16];
    __shared__ float gate_buf[512];      // [i|ste|c|o] x 128
    __shared__ float partial_buf[512];   // half-1 matvec partials
    __shared__ float fre_buf[16];
    __shared__ float h_buf[128];

    const int tid  = threadIdx.x;
    const int lane = tid & 63;
    const int half = tid >> 9;
    const int c    = tid & 511;
    const int m    = c >> 7;
    const int j    = c & 127;
    const int hh   = tid >> 3;     // 0..127
    const int fsel = tid & 7;      // freqs fsel, fsel+8
    const int b    = blockIdx.x;

    // one-time LDS init
    for (int e = tid; e < 2048; e += 1024) {
        int k = e >> 4, col = e & 15;
        ufre_t[col * 132 + k] = Ufre[e];
    }
    if (tid < 16) {
        float ang = 6.283185307179586f * (float)tid * (1.0f / 16.0f);
        costab[tid] = cosf(ang);
        sintab[tid] = sinf(ang);
    }
    if (tid < 128) h_buf[tid] = 0.0f;

    // 64-element half-column of U in registers (coalesced over j).
    // volatile loads: must execute exactly once, pre-loop; with the 128-VGPR
    // budget from amdgpu_waves_per_eu(4,4) the values stay register-resident.
    const float* Uptr = (m == 0) ? Ui : (m == 1) ? Uste : (m == 2) ? Uc : Uo;
    const volatile float* Uv = (const volatile float*)Uptr;
    float Ucol[64];
#pragma unroll
    for (int k = 0; k < 64; k++) Ucol[k] = Uv[(half * 64 + k) * 128 + j];
    asm volatile("" ::: "memory");   // keep the loads anchored above the loop

    const float ua0 = Ua[fsel];
    const float ua1 = Ua[fsel + 8];
    const float ba  = ba_g[hh];

    float hA = 0.0f;               // h[half*64 + lane], wave-replicated
    float Sre0 = 0.f, Sim0 = 0.f, Sre1 = 0.f, Sim1 = 0.f;
    int idx0 = 0, idx1 = 0;

    __syncthreads();

    const float* pr = P + (size_t)b * 128 * 528;
    for (int t = 0; t < 128; t++) {
        // global prefetch (consumed after barrier 1 — latency hidden by matvec)
        const float xpre = (half == 0) ? pr[c] : pr[512 + (c >> 5)];

        // ---- matvec partial: acc = sum_{k in half} h[k] * U[k][j] ----
        float a0 = 0.f, a1 = 0.f;
#pragma unroll
        for (int kk = 0; kk < 64; kk += 2) {
            float s0 = __uint_as_float(__builtin_amdgcn_readlane(__float_as_uint(hA), kk));
            float s1 = __uint_as_float(__builtin_amdgcn_readlane(__float_as_uint(hA), kk + 1));
            a0 = fmaf(s0, Ucol[kk],     a0);
            a1 = fmaf(s1, Ucol[kk + 1], a1);
        }
        float acc = a0 + a1;

        if (half) partial_buf[c] = acc;
        __syncthreads();  // B1: partials visible

        if (half == 0) {
            float z = acc + partial_buf[c] + xpre;
            float g = (m == 2) ? tanhf(z) : hsig_f(z);
            gate_buf[c] = g;
        } else {
            // fre gate: col = c>>5, 32 threads per col, 4 k's each (h_buf still old h)
            const int col = c >> 5, kg = c & 31;
            float4 hv = *(const float4*)(&h_buf[kg * 4]);
            float4 uv = *(const float4*)(&ufre_t[col * 132 + kg * 4]);
            float p = fmaf(hv.x, uv.x, fmaf(hv.y, uv.y, fmaf(hv.z, uv.z, hv.w * uv.w)));
#pragma unroll
            for (int off = 1; off <= 16; off <<= 1) p += __shfl_xor(p, off, 64);
            if (kg == 0) fre_buf[col] = hsig_f(p + xpre);
        }
        __syncthreads();  // B2: gates + fre ready

        // ---- state update: thread owns (hh, freqs fsel & fsel+8) ----
        {
            float iv = gate_buf[hh];
            float sv = gate_buf[128 + hh];
            float tc = gate_buf[256 + hh];
            float ov = gate_buf[384 + hh];
            float cg = iv * tc;

            idx0 = (idx0 + fsel) & 15;
            idx1 = (idx1 + fsel + 8) & 15;

            float f0v = sv * fre_buf[fsel];
            float f1v = sv * fre_buf[fsel + 8];
            Sre0 = fmaf(f0v, Sre0, cg * costab[idx0]);
            Sim0 = fmaf(f0v, Sim0, cg * sintab[idx0]);
            Sre1 = fmaf(f1v, Sre1, cg * costab[idx1]);
            Sim1 = fmaf(f1v, Sim1, cg * sintab[idx1]);

            float aacc = fmaf(Sre0, Sre0, Sim0 * Sim0) * ua0;
            aacc = fmaf(fmaf(Sre1, Sre1, Sim1 * Sim1), ua1, aacc);
            aacc += __shfl_xor(aacc, 1, 64);
            aacc += __shfl_xor(aacc, 2, 64);
            aacc += __shfl_xor(aacc, 4, 64);
            if (fsel == 0) {
                float a = tanhf(aacc + ba);
                h_buf[hh] = ov * a;
            }
        }
        __syncthreads();  // B3: h ready
        hA = h_buf[half * 64 + lane];
        pr += 528;
    }

    // ---- output: out[b] = h @ W_sym + b_sym ----
    if (tid < 64) {
        float v = fmaf(h_buf[lane], Wsym[lane], h_buf[64 + lane] * Wsym[64 + lane]);
#pragma unroll
        for (int off = 1; off <= 32; off <<= 1) v += __shfl_xor(v, off, 64);
        if (lane == 0) out[b] = v + bsym[0];
    }
}

extern "C" void kernel_launch(void* const* d_in, const int* in_sizes, int n_in,
                              void* d_out, int out_size, void* d_ws, size_t ws_size,
                              hipStream_t stream) {
    const float* input = (const float*)d_in[0];
    const float* W_i   = (const float*)d_in[1];
    const float* U_i   = (const float*)d_in[2];
    const float* b_i   = (const float*)d_in[3];
    const float* W_ste = (const float*)d_in[4];
    const float* U_ste = (const float*)d_in[5];
    const float* b_ste = (const float*)d_in[6];
    const float* W_fre = (const float*)d_in[7];
    const float* U_fre = (const float*)d_in[8];
    const float* b_fre = (const float*)d_in[9];
    const float* W_c   = (const float*)d_in[10];
    const float* U_c   = (const float*)d_in[11];
    const float* b_c   = (const float*)d_in[12];
    const float* W_o   = (const float*)d_in[13];
    const float* U_o   = (const float*)d_in[14];
    const float* b_o   = (const float*)d_in[15];
    const float* U_a   = (const float*)d_in[16];
    const float* b_a   = (const float*)d_in[17];
    const float* W_sym = (const float*)d_in[18];
    const float* b_sym = (const float*)d_in[19];

    float* P = (float*)d_ws;  // 32768 x 528 fp32 = 69.2 MB

    proj_gemm<<<512, 256, 0, stream>>>(
        input, W_i, W_ste, W_c, W_o, W_fre,
        b_i, b_ste, b_c, b_o, b_fre, P);

    recur_kernel<<<256, 1024, 0, stream>>>(
        P, U_i, U_ste, U_c, U_o, U_fre,
        U_a, b_a, W_sym, b_sym, (float*)d_out);
}